// Round 1
// baseline (5903.394 us; speedup 1.0000x reference)
//
#include <hip/hip_runtime.h>
#include <math.h>

// Soft k-means via bf16 hi/lo 3-product MFMA emulation of fp32.
// N=100000, D=512, K=256, temp=30, 11 iterations.
//
// v2 strategy: precompute normalized data as bf16 hi/lo planes in BOTH
// [i][d] (dist A-operand) and [d][i] (update B-operand) layouts; dist
// stores r transposed-packed [k][i] so update can load MFMA fragments
// DIRECTLY from global memory: no LDS staging, no barriers, no per-iter
// fp32->bf16 conversion in the two big GEMM kernels.
// Tiered by ws_size; falls back to the verified baseline pipeline.

#define DIMD 512
#define KCL 256
#define NSPLIT 96   // old update kernel i-splits
#define NCH_V2 128  // v2 update i-chunks (chunk rounded to 32)

typedef __attribute__((ext_vector_type(8))) short short8;
typedef __attribute__((ext_vector_type(4))) short short4v;
typedef __attribute__((ext_vector_type(4))) float float4v;

__device__ __forceinline__ short f2bf(float x) {
  union { float f; unsigned u; } v; v.f = x;
  unsigned r = v.u + 0x7fff + ((v.u >> 16) & 1);   // round-to-nearest-even
  return (short)(r >> 16);
}
__device__ __forceinline__ float bf2f(short b) {
  union { unsigned u; float f; } v;
  v.u = ((unsigned)(unsigned short)b) << 16;
  return v.f;
}

// -------- row norms of data + optional [i][d] hi/lo planes --------
__global__ void row_norms_conv_k(const float* __restrict__ x,
                                 float* __restrict__ inv_norm,
                                 short* __restrict__ pl_hi,
                                 short* __restrict__ pl_lo, int n,
                                 int do_planes) {
  int wave = threadIdx.x >> 6;
  int lane = threadIdx.x & 63;
  int row = blockIdx.x * 4 + wave;
  if (row >= n) return;
  const float* p = x + (size_t)row * DIMD + lane * 8;
  float4 a = *(const float4*)p;
  float4 b = *(const float4*)(p + 4);
  float s = a.x*a.x + a.y*a.y + a.z*a.z + a.w*a.w
          + b.x*b.x + b.y*b.y + b.z*b.z + b.w*b.w;
#pragma unroll
  for (int m = 32; m >= 1; m >>= 1) s += __shfl_xor(s, m);
  float inv = 1.0f / (sqrtf(s) + 1e-6f);
  if (lane == 0) inv_norm[row] = inv;
  if (do_planes) {
    float vv[8] = {a.x*inv, a.y*inv, a.z*inv, a.w*inv,
                   b.x*inv, b.y*inv, b.z*inv, b.w*inv};
    short8 hv, lv;
#pragma unroll
    for (int j = 0; j < 8; ++j) {
      short h = f2bf(vv[j]);
      hv[j] = h;
      lv[j] = f2bf(vv[j] - bf2f(h));
    }
    *(short8*)(pl_hi + (size_t)row * DIMD + lane * 8) = hv;
    *(short8*)(pl_lo + (size_t)row * DIMD + lane * 8) = lv;
  }
}

// -------- normalized data -> transposed hi/lo planes [d][i] --------
__global__ __launch_bounds__(256) void transpose_k(
    const float* __restrict__ x, const float* __restrict__ inv_norm,
    short* __restrict__ xT_hi, short* __restrict__ xT_lo, int n) {
  __shared__ unsigned lds[64][65];  // packed (hi<<16|lo), [d][i], +1 pad
  int t = threadIdx.x;
  int i0 = blockIdx.x * 64, d0 = blockIdx.y * 64;
  {
    int il = t >> 2, seg = (t & 3) * 16;
    int gi = i0 + il; if (gi > n - 1) gi = n - 1;
    float sc = inv_norm[gi];
    const float* p = x + (size_t)gi * DIMD + d0 + seg;
    float4 f0 = *(const float4*)p;
    float4 f1 = *(const float4*)(p + 4);
    float4 f2 = *(const float4*)(p + 8);
    float4 f3 = *(const float4*)(p + 12);
    float vv[16] = {f0.x,f0.y,f0.z,f0.w, f1.x,f1.y,f1.z,f1.w,
                    f2.x,f2.y,f2.z,f2.w, f3.x,f3.y,f3.z,f3.w};
#pragma unroll
    for (int j = 0; j < 16; ++j) {
      float v = vv[j] * sc;
      short h = f2bf(v);
      short l = f2bf(v - bf2f(h));
      lds[seg + j][il] =
          ((unsigned)(unsigned short)h << 16) | (unsigned short)l;
    }
  }
  __syncthreads();
  {
    int dl = t >> 2, isg = (t & 3) * 16;
    if (i0 + isg < n) {  // n % 16 == 0: whole 16-col segments valid/invalid
      unsigned u[16];
#pragma unroll
      for (int j = 0; j < 16; ++j) u[j] = lds[dl][isg + j];
      union S8u { short8 s; unsigned w[4]; };
      S8u h0, h1, l0, l1;
#pragma unroll
      for (int j = 0; j < 4; ++j) {
        h0.w[j] = __builtin_amdgcn_perm(u[2*j+1], u[2*j], 0x07060302u);
        l0.w[j] = __builtin_amdgcn_perm(u[2*j+1], u[2*j], 0x05040100u);
        h1.w[j] = __builtin_amdgcn_perm(u[2*j+9], u[2*j+8], 0x07060302u);
        l1.w[j] = __builtin_amdgcn_perm(u[2*j+9], u[2*j+8], 0x05040100u);
      }
      size_t rb = (size_t)(d0 + dl) * n + i0 + isg;
      *(short8*)(xT_hi + rb) = h0.s;
      *(short8*)(xT_hi + rb + 8) = h1.s;
      *(short8*)(xT_lo + rb) = l0.s;
      *(short8*)(xT_lo + rb + 8) = l1.s;
    }
  }
}

// -------- mu_n = normalize(mu_src [/ colsum]) -> bf16 hi/lo; zero accums ----
__global__ void mu_norm_k(const float* __restrict__ mu_src,
                          const float* __restrict__ colsum_in,
                          short* __restrict__ mu_hi, short* __restrict__ mu_lo,
                          float* __restrict__ mu_acc_z,
                          float* __restrict__ colsum_z, int use_colsum) {
  int k = blockIdx.x;
  int t = threadIdx.x;
  float inv_c = 1.0f;
  if (use_colsum) inv_c = 1.0f / colsum_in[k];
  float v0 = mu_src[k * DIMD + t] * inv_c;
  float v1 = mu_src[k * DIMD + t + 256] * inv_c;
  float s = v0 * v0 + v1 * v1;
#pragma unroll
  for (int m = 32; m >= 1; m >>= 1) s += __shfl_xor(s, m);
  __shared__ float sred[4];
  int lane = t & 63, wv = t >> 6;
  if (lane == 0) sred[wv] = s;
  __syncthreads();
  s = sred[0] + sred[1] + sred[2] + sred[3];
  float inv = 1.0f / (sqrtf(s) + 1e-6f);
  float w0 = v0 * inv, w1 = v1 * inv;
  short h0 = f2bf(w0), h1 = f2bf(w1);
  mu_hi[k * DIMD + t] = h0;
  mu_hi[k * DIMD + t + 256] = h1;
  mu_lo[k * DIMD + t] = f2bf(w0 - bf2f(h0));
  mu_lo[k * DIMD + t + 256] = f2bf(w1 - bf2f(h1));
  mu_acc_z[k * DIMD + t] = 0.0f;
  mu_acc_z[k * DIMD + t + 256] = 0.0f;
  if (t == 0) colsum_z[k] = 0.0f;
}

// -------- out_mu = mu_acc / colsum --------
__global__ void final_mu_k(const float* __restrict__ mu_acc,
                           const float* __restrict__ colsum,
                           float* __restrict__ out) {
  int k = blockIdx.x;
  int t = threadIdx.x;
  float ic = 1.0f / colsum[k];
  out[k * DIMD + t] = mu_acc[k * DIMD + t] * ic;
  out[k * DIMD + t + 256] = mu_acc[k * DIMD + t + 256] * ic;
}

// -------- dist = data_n @ mu_n^T ; r = softmax(temp*dist) ; colsum += -------
// Block: 64 i-rows x 256 k-cols, 256 threads = 4 waves; wave wc owns cols
// wc*64..+63 as 4x4 tiles of 16x16x32 MFMA, bf16 hi/lo 3-product.
// PRE=1: A,B fragments loaded directly from global hi/lo planes (no LDS
//        staging, no main-loop barriers). PRE=0: baseline LDS staging.
// TS=1: packed r stored transposed [k][i]; TS=0: baseline [i][k].
template <int PRE, int TS>
__global__ __launch_bounds__(256, 2) void dist_k(
    const float* __restrict__ data, const float* __restrict__ inv_norm,
    const short* __restrict__ pl_hi, const short* __restrict__ pl_lo,
    const short* __restrict__ mu_hi, const short* __restrict__ mu_lo,
    unsigned* __restrict__ r_pack, float* __restrict__ r_f32,
    unsigned* __restrict__ rt_also, int write_f32,
    float* __restrict__ colsum, const float* __restrict__ temp_p, int n) {
  __shared__ __align__(16) float red[64][4];

  int t = threadIdx.x;
  int wave = t >> 6, lane = t & 63, q = lane >> 4, lx = lane & 15;
  int i0 = blockIdx.x * 64;

  float4v acc[4][4];
#pragma unroll
  for (int mt = 0; mt < 4; ++mt)
#pragma unroll
    for (int nt = 0; nt < 4; ++nt) acc[mt][nt] = (float4v)0.0f;

  if constexpr (PRE) {
    const short *aH[4], *aL[4], *bH[4], *bL[4];
#pragma unroll
    for (int mt = 0; mt < 4; ++mt) {
      int gi = i0 + mt * 16 + lx;
      if (gi > n - 1) gi = n - 1;
      size_t o = (size_t)gi * DIMD + q * 8;
      aH[mt] = pl_hi + o;
      aL[mt] = pl_lo + o;
    }
#pragma unroll
    for (int nt = 0; nt < 4; ++nt) {
      size_t o = (size_t)(wave * 64 + nt * 16 + lx) * DIMD + q * 8;
      bH[nt] = mu_hi + o;
      bL[nt] = mu_lo + o;
    }
#pragma unroll 2
    for (int ch = 0; ch < 16; ++ch) {
      int d0 = ch * 32;
      short8 ah[4], al[4], bh[4], bl[4];
#pragma unroll
      for (int mt = 0; mt < 4; ++mt) {
        ah[mt] = *(const short8*)(aH[mt] + d0);
        al[mt] = *(const short8*)(aL[mt] + d0);
      }
#pragma unroll
      for (int nt = 0; nt < 4; ++nt) {
        bh[nt] = *(const short8*)(bH[nt] + d0);
        bl[nt] = *(const short8*)(bL[nt] + d0);
      }
#pragma unroll
      for (int mt = 0; mt < 4; ++mt)
#pragma unroll
        for (int nt = 0; nt < 4; ++nt) {
          acc[mt][nt] = __builtin_amdgcn_mfma_f32_16x16x32_bf16(
              ah[mt], bh[nt], acc[mt][nt], 0, 0, 0);
          acc[mt][nt] = __builtin_amdgcn_mfma_f32_16x16x32_bf16(
              ah[mt], bl[nt], acc[mt][nt], 0, 0, 0);
          acc[mt][nt] = __builtin_amdgcn_mfma_f32_16x16x32_bf16(
              al[mt], bh[nt], acc[mt][nt], 0, 0, 0);
        }
    }
  } else {
    // rows: [i][d 0..31 = hi, 32..63 = lo], stride 72 (144 B)
    __shared__ __align__(16) short a_lds[64][72];
    __shared__ __align__(16) short b_lds[256][72];
    for (int ch = 0; ch < 16; ++ch) {
      int d0 = ch * 32;
      {
        int row = t >> 2, seg = t & 3;
        int gi = i0 + row;
        if (gi > n - 1) gi = n - 1;
        const float* p = data + (size_t)gi * DIMD + d0 + seg * 8;
        float4 x0 = *(const float4*)p;
        float4 x1 = *(const float4*)(p + 4);
        float sc = inv_norm[gi];
        float vv[8] = {x0.x * sc, x0.y * sc, x0.z * sc, x0.w * sc,
                       x1.x * sc, x1.y * sc, x1.z * sc, x1.w * sc};
        short8 hv, lv;
#pragma unroll
        for (int j = 0; j < 8; ++j) {
          short h = f2bf(vv[j]);
          hv[j] = h;
          lv[j] = f2bf(vv[j] - bf2f(h));
        }
        *(short8*)&a_lds[row][seg * 8] = hv;
        *(short8*)&a_lds[row][32 + seg * 8] = lv;
      }
      {
        int seg = t & 3, kb = t >> 2;
#pragma unroll
        for (int rep = 0; rep < 4; ++rep) {
          int k = rep * 64 + kb;
          short8 h = *(const short8*)(mu_hi + (size_t)k * DIMD + d0 + seg * 8);
          short8 l = *(const short8*)(mu_lo + (size_t)k * DIMD + d0 + seg * 8);
          *(short8*)&b_lds[k][seg * 8] = h;
          *(short8*)&b_lds[k][32 + seg * 8] = l;
        }
      }
      __syncthreads();
      short8 ah[4], al[4], bh[4], bl[4];
#pragma unroll
      for (int mt = 0; mt < 4; ++mt) {
        ah[mt] = *(const short8*)&a_lds[mt * 16 + lx][q * 8];
        al[mt] = *(const short8*)&a_lds[mt * 16 + lx][32 + q * 8];
      }
#pragma unroll
      for (int nt = 0; nt < 4; ++nt) {
        int kr = wave * 64 + nt * 16 + lx;
        bh[nt] = *(const short8*)&b_lds[kr][q * 8];
        bl[nt] = *(const short8*)&b_lds[kr][32 + q * 8];
      }
#pragma unroll
      for (int mt = 0; mt < 4; ++mt)
#pragma unroll
        for (int nt = 0; nt < 4; ++nt) {
          acc[mt][nt] = __builtin_amdgcn_mfma_f32_16x16x32_bf16(
              ah[mt], bh[nt], acc[mt][nt], 0, 0, 0);
          acc[mt][nt] = __builtin_amdgcn_mfma_f32_16x16x32_bf16(
              ah[mt], bl[nt], acc[mt][nt], 0, 0, 0);
          acc[mt][nt] = __builtin_amdgcn_mfma_f32_16x16x32_bf16(
              al[mt], bh[nt], acc[mt][nt], 0, 0, 0);
        }
      __syncthreads();
    }
  }

  // ---- softmax over K=256 per row; |30*dist| <= ~30.5 so no max-shift ----
  float tempv = temp_p[0];
  float rs[4][4];
#pragma unroll
  for (int mt = 0; mt < 4; ++mt)
#pragma unroll
    for (int reg = 0; reg < 4; ++reg) {
      float s = 0.0f;
#pragma unroll
      for (int nt = 0; nt < 4; ++nt) {
        float e = __expf(tempv * acc[mt][nt][reg]);
        acc[mt][nt][reg] = e;
        s += e;
      }
      s += __shfl_xor(s, 1);
      s += __shfl_xor(s, 2);
      s += __shfl_xor(s, 4);
      s += __shfl_xor(s, 8);
      rs[mt][reg] = s;
    }
  if (lx == 0) {
#pragma unroll
    for (int mt = 0; mt < 4; ++mt)
#pragma unroll
      for (int reg = 0; reg < 4; ++reg)
        red[mt * 16 + q * 4 + reg][wave] = rs[mt][reg];
  }
  __syncthreads();

  float cs[4] = {0.0f, 0.0f, 0.0f, 0.0f};
#pragma unroll
  for (int mt = 0; mt < 4; ++mt)
#pragma unroll
    for (int reg = 0; reg < 4; ++reg) {
      int row = mt * 16 + q * 4 + reg;
      float4 v = *(const float4*)&red[row][0];
      float is = 1.0f / (v.x + v.y + v.z + v.w);
      int gi = i0 + row;
      bool ok = gi < n;
#pragma unroll
      for (int nt = 0; nt < 4; ++nt) {
        float r = acc[mt][nt][reg] * is;
        acc[mt][nt][reg] = r;
        if (ok) cs[nt] += r;
      }
      if (ok) {
        if (write_f32) {
#pragma unroll
          for (int nt = 0; nt < 4; ++nt)
            r_f32[(size_t)gi * KCL + wave * 64 + nt * 16 + lx] =
                acc[mt][nt][reg];
          if (rt_also) {
#pragma unroll
            for (int nt = 0; nt < 4; ++nt) {
              float r = acc[mt][nt][reg];
              short h = f2bf(r);
              short l = f2bf(r - bf2f(h));
              rt_also[(size_t)(wave * 64 + nt * 16 + lx) * n + gi] =
                  ((unsigned)(unsigned short)h << 16) | (unsigned short)l;
            }
          }
        } else {
#pragma unroll
          for (int nt = 0; nt < 4; ++nt) {
            float r = acc[mt][nt][reg];
            short h = f2bf(r);
            short l = f2bf(r - bf2f(h));
            unsigned u =
                ((unsigned)(unsigned short)h << 16) | (unsigned short)l;
            if constexpr (TS)
              r_pack[(size_t)(wave * 64 + nt * 16 + lx) * n + gi] = u;
            else
              r_pack[(size_t)gi * KCL + wave * 64 + nt * 16 + lx] = u;
          }
        }
      }
    }
#pragma unroll
  for (int nt = 0; nt < 4; ++nt) {
    cs[nt] += __shfl_xor(cs[nt], 16);
    cs[nt] += __shfl_xor(cs[nt], 32);
  }
  if (q == 0) {
#pragma unroll
    for (int nt = 0; nt < 4; ++nt)
      atomicAdd(&colsum[wave * 64 + nt * 16 + lx], cs[nt]);
  }
}

// -------- mu_acc += r^T @ data_n, direct-from-global fragments --------
// rT: packed (hi<<16|lo) [k][i]; xT planes [d][i]. Block 128k x 128d,
// 256 threads = 4 waves (2x2 of 64x64 wave tiles). No LDS, no barriers.
// Grid 8*NCH_V2; id decode puts all 8 tiles of one i-chunk on one XCD.
__global__ __launch_bounds__(256, 2) void update_v2_k(
    const unsigned* __restrict__ rT, const short* __restrict__ xT_hi,
    const short* __restrict__ xT_lo, float* __restrict__ mu_acc, int n,
    int chunk) {
  int t = threadIdx.x, wave = t >> 6, lane = t & 63, q = lane >> 4,
      lx = lane & 15;
  int B = blockIdx.x;
  int x = B & 7, m = B >> 3, tt = m & 7, g = m >> 3;
  int c = x + 8 * g;  // chunk index; ids of chunk c all == x (mod 8) -> XCD
  int ibeg = c * chunk;
  if (ibeg >= n) return;
  int iend = ibeg + chunk;
  if (iend > n) iend = n;  // n, chunk both multiples of 32 -> full tiles
  int k0 = (tt & 1) * 128, d0 = (tt >> 1) * 128;
  int wk = wave >> 1, wd = wave & 1;

  const unsigned* abase[4];
  const short* bhb[4];
  const short* blb[4];
#pragma unroll
  for (int mt = 0; mt < 4; ++mt)
    abase[mt] = rT + (size_t)(k0 + wk * 64 + mt * 16 + lx) * n + q * 8;
#pragma unroll
  for (int nt = 0; nt < 4; ++nt) {
    size_t dr = (size_t)(d0 + wd * 64 + nt * 16 + lx) * n + q * 8;
    bhb[nt] = xT_hi + dr;
    blb[nt] = xT_lo + dr;
  }

  float4v acc[4][4];
#pragma unroll
  for (int mt = 0; mt < 4; ++mt)
#pragma unroll
    for (int nt = 0; nt < 4; ++nt) acc[mt][nt] = (float4v)0.0f;

  union S8u { short8 s; unsigned w[4]; };
  for (int ib = ibeg; ib < iend; ib += 32) {
    short8 bh[4], bl[4];
#pragma unroll
    for (int nt = 0; nt < 4; ++nt) {
      bh[nt] = *(const short8*)(bhb[nt] + ib);
      bl[nt] = *(const short8*)(blb[nt] + ib);
    }
    S8u ah[4], al[4];
#pragma unroll
    for (int mt = 0; mt < 4; ++mt) {
      uint4 p0 = *(const uint4*)(abase[mt] + ib);
      uint4 p1 = *(const uint4*)(abase[mt] + ib + 4);
      unsigned pp[8] = {p0.x, p0.y, p0.z, p0.w, p1.x, p1.y, p1.z, p1.w};
#pragma unroll
      for (int j = 0; j < 4; ++j) {
        ah[mt].w[j] =
            __builtin_amdgcn_perm(pp[2 * j + 1], pp[2 * j], 0x07060302u);
        al[mt].w[j] =
            __builtin_amdgcn_perm(pp[2 * j + 1], pp[2 * j], 0x05040100u);
      }
    }
#pragma unroll
    for (int mt = 0; mt < 4; ++mt)
#pragma unroll
      for (int nt = 0; nt < 4; ++nt) {
        acc[mt][nt] = __builtin_amdgcn_mfma_f32_16x16x32_bf16(
            ah[mt].s, bh[nt], acc[mt][nt], 0, 0, 0);
        acc[mt][nt] = __builtin_amdgcn_mfma_f32_16x16x32_bf16(
            ah[mt].s, bl[nt], acc[mt][nt], 0, 0, 0);
        acc[mt][nt] = __builtin_amdgcn_mfma_f32_16x16x32_bf16(
            al[mt].s, bh[nt], acc[mt][nt], 0, 0, 0);
      }
  }
#pragma unroll
  for (int mt = 0; mt < 4; ++mt)
#pragma unroll
    for (int nt = 0; nt < 4; ++nt)
#pragma unroll
      for (int reg = 0; reg < 4; ++reg) {
        int k = k0 + wk * 64 + mt * 16 + q * 4 + reg;
        int d = d0 + wd * 64 + nt * 16 + lx;
        atomicAdd(&mu_acc[(size_t)k * DIMD + d], acc[mt][nt][reg]);
      }
}

// -------- baseline update (LDS transpose staging) — final-iter / fallback ---
__global__ __launch_bounds__(256) void update_mfma_k(
    const unsigned* __restrict__ r_src, int r_is_f32,
    const float* __restrict__ data, const float* __restrict__ inv_norm,
    float* __restrict__ mu_acc, int n) {
  __shared__ __align__(16) short rT[128][72];
  __shared__ __align__(16) short xT[128][72];

  int t = threadIdx.x, wave = t >> 6, lane = t & 63, q = lane >> 4,
      lx = lane & 15;
  int bx = blockIdx.x;
  int k0 = (bx & 1) * 128, d0 = (bx >> 1) * 128;
  int ns = blockIdx.y;
  int chunk = (n + NSPLIT - 1) / NSPLIT;
  int ibeg = ns * chunk;
  int iend = ibeg + chunk;
  if (iend > n) iend = n;
  int wk = wave >> 1, wd = wave & 1;
  int iq = t >> 5, kq = t & 31;

  float4v acc[4][4];
#pragma unroll
  for (int mt = 0; mt < 4; ++mt)
#pragma unroll
    for (int nt = 0; nt < 4; ++nt) acc[mt][nt] = (float4v)0.0f;

  for (int ib = ibeg; ib < iend; ib += 32) {
    {
      short h[4][4], l[4][4];
#pragma unroll
      for (int ii = 0; ii < 4; ++ii) {
        int gi = ib + iq * 4 + ii;
        uint4 u = make_uint4(0u, 0u, 0u, 0u);
        if (gi < iend)
          u = *(const uint4*)(r_src + (size_t)gi * KCL + k0 + kq * 4);
        unsigned uu[4] = {u.x, u.y, u.z, u.w};
        if (r_is_f32) {
#pragma unroll
          for (int kk = 0; kk < 4; ++kk) {
            union { unsigned u; float f; } cvt; cvt.u = uu[kk];
            short hh = f2bf(cvt.f);
            h[ii][kk] = hh;
            l[ii][kk] = f2bf(cvt.f - bf2f(hh));
          }
        } else {
#pragma unroll
          for (int kk = 0; kk < 4; ++kk) {
            h[ii][kk] = (short)(uu[kk] >> 16);
            l[ii][kk] = (short)(uu[kk] & 0xffffu);
          }
        }
      }
#pragma unroll
      for (int kk = 0; kk < 4; ++kk) {
        short4v vh = {h[0][kk], h[1][kk], h[2][kk], h[3][kk]};
        short4v vl = {l[0][kk], l[1][kk], l[2][kk], l[3][kk]};
        *(short4v*)&rT[kq * 4 + kk][iq * 4] = vh;
        *(short4v*)&rT[kq * 4 + kk][32 + iq * 4] = vl;
      }
    }
    {
      short h[4][4], l[4][4];
#pragma unroll
      for (int ii = 0; ii < 4; ++ii) {
        int gi = ib + iq * 4 + ii;
        float4 xx = make_float4(0.f, 0.f, 0.f, 0.f);
        float sc = 0.0f;
        if (gi < iend) {
          xx = *(const float4*)(data + (size_t)gi * DIMD + d0 + kq * 4);
          sc = inv_norm[gi];
        }
        float vv[4] = {xx.x * sc, xx.y * sc, xx.z * sc, xx.w * sc};
#pragma unroll
        for (int kk = 0; kk < 4; ++kk) {
          short hh = f2bf(vv[kk]);
          h[ii][kk] = hh;
          l[ii][kk] = f2bf(vv[kk] - bf2f(hh));
        }
      }
#pragma unroll
      for (int kk = 0; kk < 4; ++kk) {
        short4v vh = {h[0][kk], h[1][kk], h[2][kk], h[3][kk]};
        short4v vl = {l[0][kk], l[1][kk], l[2][kk], l[3][kk]};
        *(short4v*)&xT[kq * 4 + kk][iq * 4] = vh;
        *(short4v*)&xT[kq * 4 + kk][32 + iq * 4] = vl;
      }
    }
    __syncthreads();
    short8 ah[4], al[4], bh[4], bl[4];
#pragma unroll
    for (int mt = 0; mt < 4; ++mt) {
      int kr = wk * 64 + mt * 16 + lx;
      ah[mt] = *(const short8*)&rT[kr][q * 8];
      al[mt] = *(const short8*)&rT[kr][32 + q * 8];
    }
#pragma unroll
    for (int nt = 0; nt < 4; ++nt) {
      int dr = wd * 64 + nt * 16 + lx;
      bh[nt] = *(const short8*)&xT[dr][q * 8];
      bl[nt] = *(const short8*)&xT[dr][32 + q * 8];
    }
#pragma unroll
    for (int mt = 0; mt < 4; ++mt)
#pragma unroll
      for (int nt = 0; nt < 4; ++nt) {
        acc[mt][nt] = __builtin_amdgcn_mfma_f32_16x16x32_bf16(
            ah[mt], bh[nt], acc[mt][nt], 0, 0, 0);
        acc[mt][nt] = __builtin_amdgcn_mfma_f32_16x16x32_bf16(
            ah[mt], bl[nt], acc[mt][nt], 0, 0, 0);
        acc[mt][nt] = __builtin_amdgcn_mfma_f32_16x16x32_bf16(
            al[mt], bh[nt], acc[mt][nt], 0, 0, 0);
      }
    __syncthreads();
  }
#pragma unroll
  for (int mt = 0; mt < 4; ++mt)
#pragma unroll
    for (int nt = 0; nt < 4; ++nt)
#pragma unroll
      for (int reg = 0; reg < 4; ++reg) {
        int k = k0 + wk * 64 + mt * 16 + q * 4 + reg;
        int d = d0 + wd * 64 + nt * 16 + lx;
        atomicAdd(&mu_acc[(size_t)k * DIMD + d], acc[mt][nt][reg]);
      }
}

extern "C" void kernel_launch(void* const* d_in, const int* in_sizes, int n_in,
                              void* d_out, int out_size, void* d_ws,
                              size_t ws_size, hipStream_t stream) {
  const float* embeds = (const float*)d_in[0];
  const float* temp_p = (const float*)d_in[1];
  const float* init = (const float*)d_in[2];
  int n = in_sizes[0] / DIMD;  // 100000

  float* out_mu = (float*)d_out;                       // [256*512]
  float* out_r = (float*)d_out + (size_t)KCL * DIMD;   // [n*256]

  char* base = (char*)d_ws;
  size_t off = 0;
  auto alloc = [&](size_t bytes) {
    char* p = base + off;
    off += (bytes + 255) & ~(size_t)255;
    return p;
  };
  float* inv_norm = (float*)alloc((size_t)n * 4);
  float* mu_acc = (float*)alloc((size_t)KCL * DIMD * 4);
  float* colsum = (float*)alloc(1024);
  short* mu_hi = (short*)alloc((size_t)KCL * DIMD * 2);
  short* mu_lo = (short*)alloc((size_t)KCL * DIMD * 2);

  const size_t PL = (size_t)n * DIMD * 2;   // one bf16 plane
  const size_t RTB = (size_t)n * KCL * 4;   // packed rT scratch
  const size_t SLACK = 4096;

  short *xT_hi = nullptr, *xT_lo = nullptr, *pl_hi = nullptr, *pl_lo = nullptr;
  unsigned* rT2 = nullptr;
  int tier = 0;
  if (off + 2 * PL + SLACK <= ws_size) {
    xT_hi = (short*)alloc(PL);
    xT_lo = (short*)alloc(PL);
    tier = 1;
  }
  if (tier == 1 && off + 2 * PL + SLACK <= ws_size) {
    pl_hi = (short*)alloc(PL);
    pl_lo = (short*)alloc(PL);
    tier = 2;
  }
  if (tier == 2 && off + RTB + SLACK <= ws_size) {
    rT2 = (unsigned*)alloc(RTB);
    tier = 3;
  }

  row_norms_conv_k<<<(n + 3) / 4, 256, 0, stream>>>(embeds, inv_norm, pl_hi,
                                                    pl_lo, n, tier >= 2);
  if (tier >= 1)
    transpose_k<<<dim3((n + 63) / 64, DIMD / 64), 256, 0, stream>>>(
        embeds, inv_norm, xT_hi, xT_lo, n);
  mu_norm_k<<<KCL, 256, 0, stream>>>(init, colsum, mu_hi, mu_lo, mu_acc,
                                     colsum, 0);

  int chunk_v2 = (((n + NCH_V2 - 1) / NCH_V2) + 31) & ~31;
  int dist_grid = (n + 63) / 64;

  for (int it = 0; it <= 10; ++it) {
    int wf32 = (it == 10) ? 1 : 0;
    unsigned* rta = (wf32 && tier >= 3) ? rT2 : nullptr;
    if (tier >= 2)
      dist_k<1, 1><<<dist_grid, 256, 0, stream>>>(
          embeds, inv_norm, pl_hi, pl_lo, mu_hi, mu_lo, (unsigned*)out_r,
          out_r, rta, wf32, colsum, temp_p, n);
    else if (tier == 1)
      dist_k<0, 1><<<dist_grid, 256, 0, stream>>>(
          embeds, inv_norm, pl_hi, pl_lo, mu_hi, mu_lo, (unsigned*)out_r,
          out_r, nullptr, wf32, colsum, temp_p, n);
    else
      dist_k<0, 0><<<dist_grid, 256, 0, stream>>>(
          embeds, inv_norm, pl_hi, pl_lo, mu_hi, mu_lo, (unsigned*)out_r,
          out_r, nullptr, wf32, colsum, temp_p, n);

    if (it < 10) {
      if (tier >= 1)
        update_v2_k<<<8 * NCH_V2, 256, 0, stream>>>(
            (const unsigned*)out_r, xT_hi, xT_lo, mu_acc, n, chunk_v2);
      else
        update_mfma_k<<<dim3(8, NSPLIT), 256, 0, stream>>>(
            (const unsigned*)out_r, 0, embeds, inv_norm, mu_acc, n);
      mu_norm_k<<<KCL, 256, 0, stream>>>(mu_acc, colsum, mu_hi, mu_lo, mu_acc,
                                         colsum, 1);
    } else {
      if (tier >= 3)
        update_v2_k<<<8 * NCH_V2, 256, 0, stream>>>(rT2, xT_hi, xT_lo, mu_acc,
                                                    n, chunk_v2);
      else
        update_mfma_k<<<dim3(8, NSPLIT), 256, 0, stream>>>(
            (const unsigned*)out_r, 1, embeds, inv_norm, mu_acc, n);
      final_mu_k<<<KCL, 256, 0, stream>>>(mu_acc, colsum, out_mu);
    }
  }
}

// Round 2
// 4158.905 us; speedup vs baseline: 1.4195x; 1.4195x over previous
//
#include <hip/hip_runtime.h>
#include <math.h>

// Soft k-means via bf16 hi/lo 3-product MFMA emulation of fp32.
// N=100000, D=512, K=256, temp=30, 11 iterations.
//
// v3: precomputed normalized bf16 hi/lo planes in [i][d] (dist A) and
// [d][i] (update B) layouts; r stored transposed-packed [k][i].
// Both GEMM kernels use cooperative LDS staging (coalesced copies, no
// per-iteration conversion, no transpose scatter) + padded-stride LDS
// reads (2-way = free). Direct-from-global fragments (v2) were
// latency-bound and are abandoned.

#define DIMD 512
#define KCL 256
#define NSPLIT 96  // baseline update i-splits (fallback)
#define NCH3 96    // v3 update i-chunks (chunk rounded to 32)

typedef __attribute__((ext_vector_type(8))) short short8;
typedef __attribute__((ext_vector_type(4))) short short4v;
typedef __attribute__((ext_vector_type(4))) float float4v;

__device__ __forceinline__ short f2bf(float x) {
  union { float f; unsigned u; } v; v.f = x;
  unsigned r = v.u + 0x7fff + ((v.u >> 16) & 1);   // round-to-nearest-even
  return (short)(r >> 16);
}
__device__ __forceinline__ float bf2f(short b) {
  union { unsigned u; float f; } v;
  v.u = ((unsigned)(unsigned short)b) << 16;
  return v.f;
}

// -------- row norms of data + optional [i][d] hi/lo planes --------
__global__ void row_norms_conv_k(const float* __restrict__ x,
                                 float* __restrict__ inv_norm,
                                 short* __restrict__ pl_hi,
                                 short* __restrict__ pl_lo, int n,
                                 int do_planes) {
  int wave = threadIdx.x >> 6;
  int lane = threadIdx.x & 63;
  int row = blockIdx.x * 4 + wave;
  if (row >= n) return;
  const float* p = x + (size_t)row * DIMD + lane * 8;
  float4 a = *(const float4*)p;
  float4 b = *(const float4*)(p + 4);
  float s = a.x*a.x + a.y*a.y + a.z*a.z + a.w*a.w
          + b.x*b.x + b.y*b.y + b.z*b.z + b.w*b.w;
#pragma unroll
  for (int m = 32; m >= 1; m >>= 1) s += __shfl_xor(s, m);
  float inv = 1.0f / (sqrtf(s) + 1e-6f);
  if (lane == 0) inv_norm[row] = inv;
  if (do_planes) {
    float vv[8] = {a.x*inv, a.y*inv, a.z*inv, a.w*inv,
                   b.x*inv, b.y*inv, b.z*inv, b.w*inv};
    short8 hv, lv;
#pragma unroll
    for (int j = 0; j < 8; ++j) {
      short h = f2bf(vv[j]);
      hv[j] = h;
      lv[j] = f2bf(vv[j] - bf2f(h));
    }
    *(short8*)(pl_hi + (size_t)row * DIMD + lane * 8) = hv;
    *(short8*)(pl_lo + (size_t)row * DIMD + lane * 8) = lv;
  }
}

// -------- normalized data -> transposed hi/lo planes [d][i] --------
__global__ __launch_bounds__(256) void transpose_k(
    const float* __restrict__ x, const float* __restrict__ inv_norm,
    short* __restrict__ xT_hi, short* __restrict__ xT_lo, int n) {
  __shared__ unsigned lds[64][65];  // packed (hi<<16|lo), [d][i], +1 pad
  int t = threadIdx.x;
  int i0 = blockIdx.x * 64, d0 = blockIdx.y * 64;
  {
    int il = t >> 2, seg = (t & 3) * 16;
    int gi = i0 + il; if (gi > n - 1) gi = n - 1;
    float sc = inv_norm[gi];
    const float* p = x + (size_t)gi * DIMD + d0 + seg;
    float4 f0 = *(const float4*)p;
    float4 f1 = *(const float4*)(p + 4);
    float4 f2 = *(const float4*)(p + 8);
    float4 f3 = *(const float4*)(p + 12);
    float vv[16] = {f0.x,f0.y,f0.z,f0.w, f1.x,f1.y,f1.z,f1.w,
                    f2.x,f2.y,f2.z,f2.w, f3.x,f3.y,f3.z,f3.w};
#pragma unroll
    for (int j = 0; j < 16; ++j) {
      float v = vv[j] * sc;
      short h = f2bf(v);
      short l = f2bf(v - bf2f(h));
      lds[seg + j][il] =
          ((unsigned)(unsigned short)h << 16) | (unsigned short)l;
    }
  }
  __syncthreads();
  {
    int dl = t >> 2, isg = (t & 3) * 16;
    if (i0 + isg < n) {  // n % 16 == 0: whole 16-col segments valid/invalid
      unsigned u[16];
#pragma unroll
      for (int j = 0; j < 16; ++j) u[j] = lds[dl][isg + j];
      union S8u { short8 s; unsigned w[4]; };
      S8u h0, h1, l0, l1;
#pragma unroll
      for (int j = 0; j < 4; ++j) {
        h0.w[j] = __builtin_amdgcn_perm(u[2*j+1], u[2*j], 0x07060302u);
        l0.w[j] = __builtin_amdgcn_perm(u[2*j+1], u[2*j], 0x05040100u);
        h1.w[j] = __builtin_amdgcn_perm(u[2*j+9], u[2*j+8], 0x07060302u);
        l1.w[j] = __builtin_amdgcn_perm(u[2*j+9], u[2*j+8], 0x05040100u);
      }
      size_t rb = (size_t)(d0 + dl) * n + i0 + isg;
      *(short8*)(xT_hi + rb) = h0.s;
      *(short8*)(xT_hi + rb + 8) = h1.s;
      *(short8*)(xT_lo + rb) = l0.s;
      *(short8*)(xT_lo + rb + 8) = l1.s;
    }
  }
}

// -------- mu_n = normalize(mu_src [/ colsum]) -> bf16 hi/lo; zero accums ----
__global__ void mu_norm_k(const float* __restrict__ mu_src,
                          const float* __restrict__ colsum_in,
                          short* __restrict__ mu_hi, short* __restrict__ mu_lo,
                          float* __restrict__ mu_acc_z,
                          float* __restrict__ colsum_z, int use_colsum) {
  int k = blockIdx.x;
  int t = threadIdx.x;
  float inv_c = 1.0f;
  if (use_colsum) inv_c = 1.0f / colsum_in[k];
  float v0 = mu_src[k * DIMD + t] * inv_c;
  float v1 = mu_src[k * DIMD + t + 256] * inv_c;
  float s = v0 * v0 + v1 * v1;
#pragma unroll
  for (int m = 32; m >= 1; m >>= 1) s += __shfl_xor(s, m);
  __shared__ float sred[4];
  int lane = t & 63, wv = t >> 6;
  if (lane == 0) sred[wv] = s;
  __syncthreads();
  s = sred[0] + sred[1] + sred[2] + sred[3];
  float inv = 1.0f / (sqrtf(s) + 1e-6f);
  float w0 = v0 * inv, w1 = v1 * inv;
  short h0 = f2bf(w0), h1 = f2bf(w1);
  mu_hi[k * DIMD + t] = h0;
  mu_hi[k * DIMD + t + 256] = h1;
  mu_lo[k * DIMD + t] = f2bf(w0 - bf2f(h0));
  mu_lo[k * DIMD + t + 256] = f2bf(w1 - bf2f(h1));
  mu_acc_z[k * DIMD + t] = 0.0f;
  mu_acc_z[k * DIMD + t + 256] = 0.0f;
  if (t == 0) colsum_z[k] = 0.0f;
}

// -------- out_mu = mu_acc / colsum --------
__global__ void final_mu_k(const float* __restrict__ mu_acc,
                           const float* __restrict__ colsum,
                           float* __restrict__ out) {
  int k = blockIdx.x;
  int t = threadIdx.x;
  float ic = 1.0f / colsum[k];
  out[k * DIMD + t] = mu_acc[k * DIMD + t] * ic;
  out[k * DIMD + t + 256] = mu_acc[k * DIMD + t + 256] * ic;
}

// -------- dist = data_n @ mu_n^T ; r = softmax(temp*dist) ; colsum += -------
// Block: 64 i-rows x 256 k-cols, 256 threads = 4 waves; wave wc owns cols
// wc*64..+63 as 4x4 tiles of 16x16x32 MFMA, bf16 hi/lo 3-product.
// PRE=1: A-tile staged by copying precomputed bf16 planes (no conversion).
// PRE=0: A-tile staged from fp32 data with on-the-fly normalize+split.
// TS=1: packed r stored transposed [k][i]; TS=0: baseline [i][k].
template <int PRE, int TS>
__global__ __launch_bounds__(256) void dist_k(
    const float* __restrict__ data, const float* __restrict__ inv_norm,
    const short* __restrict__ pl_hi, const short* __restrict__ pl_lo,
    const short* __restrict__ mu_hi, const short* __restrict__ mu_lo,
    unsigned* __restrict__ r_pack, float* __restrict__ r_f32,
    unsigned* __restrict__ rt_also, int write_f32,
    float* __restrict__ colsum, const float* __restrict__ temp_p, int n) {
  // rows: [i][d 0..31 = hi, 32..63 = lo], stride 72 (144 B) -> 2-way reads
  __shared__ __align__(16) short a_lds[64][72];
  __shared__ __align__(16) short b_lds[256][72];
  __shared__ __align__(16) float red[64][4];

  int t = threadIdx.x;
  int wave = t >> 6, lane = t & 63, q = lane >> 4, lx = lane & 15;
  int i0 = blockIdx.x * 64;

  float4v acc[4][4];
#pragma unroll
  for (int mt = 0; mt < 4; ++mt)
#pragma unroll
    for (int nt = 0; nt < 4; ++nt) acc[mt][nt] = (float4v)0.0f;

  for (int ch = 0; ch < 16; ++ch) {
    int d0 = ch * 32;
    // ---- stage A (64 x 32) ----
    if constexpr (PRE) {
      int row = t >> 2, seg = t & 3;
      int gi = i0 + row;
      if (gi > n - 1) gi = n - 1;
      size_t o = (size_t)gi * DIMD + d0 + seg * 8;
      *(short8*)&a_lds[row][seg * 8] = *(const short8*)(pl_hi + o);
      *(short8*)&a_lds[row][32 + seg * 8] = *(const short8*)(pl_lo + o);
    } else {
      int row = t >> 2, seg = t & 3;
      int gi = i0 + row;
      if (gi > n - 1) gi = n - 1;
      const float* p = data + (size_t)gi * DIMD + d0 + seg * 8;
      float4 x0 = *(const float4*)p;
      float4 x1 = *(const float4*)(p + 4);
      float sc = inv_norm[gi];
      float vv[8] = {x0.x * sc, x0.y * sc, x0.z * sc, x0.w * sc,
                     x1.x * sc, x1.y * sc, x1.z * sc, x1.w * sc};
      short8 hv, lv;
#pragma unroll
      for (int j = 0; j < 8; ++j) {
        short h = f2bf(vv[j]);
        hv[j] = h;
        lv[j] = f2bf(vv[j] - bf2f(h));
      }
      *(short8*)&a_lds[row][seg * 8] = hv;
      *(short8*)&a_lds[row][32 + seg * 8] = lv;
    }
    // ---- stage B (256 x 32, bf16 hi/lo planes) ----
    {
      int seg = t & 3, kb = t >> 2;
#pragma unroll
      for (int rep = 0; rep < 4; ++rep) {
        int k = rep * 64 + kb;
        size_t o = (size_t)k * DIMD + d0 + seg * 8;
        *(short8*)&b_lds[k][seg * 8] = *(const short8*)(mu_hi + o);
        *(short8*)&b_lds[k][32 + seg * 8] = *(const short8*)(mu_lo + o);
      }
    }
    __syncthreads();
    short8 ah[4], al[4], bh[4], bl[4];
#pragma unroll
    for (int mt = 0; mt < 4; ++mt) {
      ah[mt] = *(const short8*)&a_lds[mt * 16 + lx][q * 8];
      al[mt] = *(const short8*)&a_lds[mt * 16 + lx][32 + q * 8];
    }
#pragma unroll
    for (int nt = 0; nt < 4; ++nt) {
      int kr = wave * 64 + nt * 16 + lx;
      bh[nt] = *(const short8*)&b_lds[kr][q * 8];
      bl[nt] = *(const short8*)&b_lds[kr][32 + q * 8];
    }
#pragma unroll
    for (int mt = 0; mt < 4; ++mt)
#pragma unroll
      for (int nt = 0; nt < 4; ++nt) {
        acc[mt][nt] = __builtin_amdgcn_mfma_f32_16x16x32_bf16(
            ah[mt], bh[nt], acc[mt][nt], 0, 0, 0);
        acc[mt][nt] = __builtin_amdgcn_mfma_f32_16x16x32_bf16(
            ah[mt], bl[nt], acc[mt][nt], 0, 0, 0);
        acc[mt][nt] = __builtin_amdgcn_mfma_f32_16x16x32_bf16(
            al[mt], bh[nt], acc[mt][nt], 0, 0, 0);
      }
    __syncthreads();
  }

  // ---- softmax over K=256 per row; |30*dist| <= ~30.5 so no max-shift ----
  float tempv = temp_p[0];
  float rs[4][4];
#pragma unroll
  for (int mt = 0; mt < 4; ++mt)
#pragma unroll
    for (int reg = 0; reg < 4; ++reg) {
      float s = 0.0f;
#pragma unroll
      for (int nt = 0; nt < 4; ++nt) {
        float e = __expf(tempv * acc[mt][nt][reg]);
        acc[mt][nt][reg] = e;
        s += e;
      }
      s += __shfl_xor(s, 1);
      s += __shfl_xor(s, 2);
      s += __shfl_xor(s, 4);
      s += __shfl_xor(s, 8);
      rs[mt][reg] = s;
    }
  if (lx == 0) {
#pragma unroll
    for (int mt = 0; mt < 4; ++mt)
#pragma unroll
      for (int reg = 0; reg < 4; ++reg)
        red[mt * 16 + q * 4 + reg][wave] = rs[mt][reg];
  }
  __syncthreads();

  float cs[4] = {0.0f, 0.0f, 0.0f, 0.0f};
#pragma unroll
  for (int mt = 0; mt < 4; ++mt)
#pragma unroll
    for (int reg = 0; reg < 4; ++reg) {
      int row = mt * 16 + q * 4 + reg;
      float4 v = *(const float4*)&red[row][0];
      float is = 1.0f / (v.x + v.y + v.z + v.w);
      int gi = i0 + row;
      bool ok = gi < n;
#pragma unroll
      for (int nt = 0; nt < 4; ++nt) {
        float r = acc[mt][nt][reg] * is;
        acc[mt][nt][reg] = r;
        if (ok) cs[nt] += r;
      }
      if (ok) {
        if (write_f32) {
#pragma unroll
          for (int nt = 0; nt < 4; ++nt)
            r_f32[(size_t)gi * KCL + wave * 64 + nt * 16 + lx] =
                acc[mt][nt][reg];
          if (rt_also) {
#pragma unroll
            for (int nt = 0; nt < 4; ++nt) {
              float r = acc[mt][nt][reg];
              short h = f2bf(r);
              short l = f2bf(r - bf2f(h));
              rt_also[(size_t)(wave * 64 + nt * 16 + lx) * n + gi] =
                  ((unsigned)(unsigned short)h << 16) | (unsigned short)l;
            }
          }
        } else {
#pragma unroll
          for (int nt = 0; nt < 4; ++nt) {
            float r = acc[mt][nt][reg];
            short h = f2bf(r);
            short l = f2bf(r - bf2f(h));
            unsigned u =
                ((unsigned)(unsigned short)h << 16) | (unsigned short)l;
            if constexpr (TS)
              r_pack[(size_t)(wave * 64 + nt * 16 + lx) * n + gi] = u;
            else
              r_pack[(size_t)gi * KCL + wave * 64 + nt * 16 + lx] = u;
          }
        }
      }
    }
#pragma unroll
  for (int nt = 0; nt < 4; ++nt) {
    cs[nt] += __shfl_xor(cs[nt], 16);
    cs[nt] += __shfl_xor(cs[nt], 32);
  }
  if (q == 0) {
#pragma unroll
    for (int nt = 0; nt < 4; ++nt)
      atomicAdd(&colsum[wave * 64 + nt * 16 + lx], cs[nt]);
  }
}

// -------- mu_acc += r^T @ data_n, LDS-staged from pre-transposed inputs ----
// rT packed [k][i] u32; xT hi/lo planes [d][i]. Block 128 k x 128 d,
// 256 threads = 4 waves (2x2 of 64x64 wave tiles). Staging = coalesced
// copy (no transpose, no conversion). Grid 8*NCH3; decode keeps all 8
// tiles of one i-chunk on one XCD (L2 reuse of r x4, x x2).
__global__ __launch_bounds__(256) void update_v3_k(
    const unsigned* __restrict__ rT, const short* __restrict__ xT_hi,
    const short* __restrict__ xT_lo, float* __restrict__ mu_acc, int n,
    int chunk) {
  __shared__ __align__(16) unsigned r_lds[128][36];  // [k][i], pad 4 (2-way)
  __shared__ __align__(16) short x_lds[128][72];     // [d][i hi|lo], pad
  int t = threadIdx.x, wave = t >> 6, lane = t & 63, q = lane >> 4,
      lx = lane & 15;
  int B = blockIdx.x;
  int x = B & 7, m = B >> 3, tt = m & 7, g = m >> 3;
  int c = x + 8 * g;  // chunk index; all 8 tiles of c share B&7 -> same XCD
  int ibeg = c * chunk;
  if (ibeg >= n) return;
  int iend = ibeg + chunk;
  if (iend > n) iend = n;  // n, chunk multiples of 32 -> full 32-i steps
  int k0 = (tt & 1) * 128, d0 = (tt >> 1) * 128;
  int wk = wave >> 1, wd = wave & 1;

  int rseg = t & 7, rb = t >> 3;   // r staging: 8 lanes/row x 16B
  int xseg = t & 3, db = t >> 2;   // x staging: 4 lanes/row x 16B per plane

  float4v acc[4][4];
#pragma unroll
  for (int mt = 0; mt < 4; ++mt)
#pragma unroll
    for (int nt = 0; nt < 4; ++nt) acc[mt][nt] = (float4v)0.0f;

  union S8u { short8 s; unsigned w[4]; };
  for (int ib = ibeg; ib < iend; ib += 32) {
    // ---- stage r tile (128 k x 32 i packed) ----
#pragma unroll
    for (int p = 0; p < 4; ++p) {
      int krow = p * 32 + rb;
      uint4 u = *(const uint4*)(rT + (size_t)(k0 + krow) * n + ib + rseg * 4);
      *(uint4*)&r_lds[krow][rseg * 4] = u;
    }
    // ---- stage x tile (128 d x 32 i hi/lo) ----
#pragma unroll
    for (int p = 0; p < 2; ++p) {
      int drow = p * 64 + db;
      size_t o = (size_t)(d0 + drow) * n + ib + xseg * 8;
      *(short8*)&x_lds[drow][xseg * 8] = *(const short8*)(xT_hi + o);
      *(short8*)&x_lds[drow][32 + xseg * 8] = *(const short8*)(xT_lo + o);
    }
    __syncthreads();
    S8u ah[4], al[4];
#pragma unroll
    for (int mt = 0; mt < 4; ++mt) {
      int kr = wk * 64 + mt * 16 + lx;
      uint4 u0 = *(const uint4*)&r_lds[kr][q * 8];
      uint4 u1 = *(const uint4*)&r_lds[kr][q * 8 + 4];
      unsigned pp[8] = {u0.x, u0.y, u0.z, u0.w, u1.x, u1.y, u1.z, u1.w};
#pragma unroll
      for (int j = 0; j < 4; ++j) {
        ah[mt].w[j] =
            __builtin_amdgcn_perm(pp[2 * j + 1], pp[2 * j], 0x07060302u);
        al[mt].w[j] =
            __builtin_amdgcn_perm(pp[2 * j + 1], pp[2 * j], 0x05040100u);
      }
    }
    short8 bh[4], bl[4];
#pragma unroll
    for (int nt = 0; nt < 4; ++nt) {
      int dr = wd * 64 + nt * 16 + lx;
      bh[nt] = *(const short8*)&x_lds[dr][q * 8];
      bl[nt] = *(const short8*)&x_lds[dr][32 + q * 8];
    }
#pragma unroll
    for (int mt = 0; mt < 4; ++mt)
#pragma unroll
      for (int nt = 0; nt < 4; ++nt) {
        acc[mt][nt] = __builtin_amdgcn_mfma_f32_16x16x32_bf16(
            ah[mt].s, bh[nt], acc[mt][nt], 0, 0, 0);
        acc[mt][nt] = __builtin_amdgcn_mfma_f32_16x16x32_bf16(
            ah[mt].s, bl[nt], acc[mt][nt], 0, 0, 0);
        acc[mt][nt] = __builtin_amdgcn_mfma_f32_16x16x32_bf16(
            al[mt].s, bh[nt], acc[mt][nt], 0, 0, 0);
      }
    __syncthreads();
  }
#pragma unroll
  for (int mt = 0; mt < 4; ++mt)
#pragma unroll
    for (int nt = 0; nt < 4; ++nt)
#pragma unroll
      for (int reg = 0; reg < 4; ++reg) {
        int k = k0 + wk * 64 + mt * 16 + q * 4 + reg;
        int d = d0 + wd * 64 + nt * 16 + lx;
        atomicAdd(&mu_acc[(size_t)k * DIMD + d], acc[mt][nt][reg]);
      }
}

// -------- baseline update (LDS transpose staging) — fallback tiers ---------
__global__ __launch_bounds__(256) void update_mfma_k(
    const unsigned* __restrict__ r_src, int r_is_f32,
    const float* __restrict__ data, const float* __restrict__ inv_norm,
    float* __restrict__ mu_acc, int n) {
  __shared__ __align__(16) short rT[128][72];
  __shared__ __align__(16) short xT[128][72];

  int t = threadIdx.x, wave = t >> 6, lane = t & 63, q = lane >> 4,
      lx = lane & 15;
  int bx = blockIdx.x;
  int k0 = (bx & 1) * 128, d0 = (bx >> 1) * 128;
  int ns = blockIdx.y;
  int chunk = (n + NSPLIT - 1) / NSPLIT;
  int ibeg = ns * chunk;
  int iend = ibeg + chunk;
  if (iend > n) iend = n;
  int wk = wave >> 1, wd = wave & 1;
  int iq = t >> 5, kq = t & 31;

  float4v acc[4][4];
#pragma unroll
  for (int mt = 0; mt < 4; ++mt)
#pragma unroll
    for (int nt = 0; nt < 4; ++nt) acc[mt][nt] = (float4v)0.0f;

  for (int ib = ibeg; ib < iend; ib += 32) {
    {
      short h[4][4], l[4][4];
#pragma unroll
      for (int ii = 0; ii < 4; ++ii) {
        int gi = ib + iq * 4 + ii;
        uint4 u = make_uint4(0u, 0u, 0u, 0u);
        if (gi < iend)
          u = *(const uint4*)(r_src + (size_t)gi * KCL + k0 + kq * 4);
        unsigned uu[4] = {u.x, u.y, u.z, u.w};
        if (r_is_f32) {
#pragma unroll
          for (int kk = 0; kk < 4; ++kk) {
            union { unsigned u; float f; } cvt; cvt.u = uu[kk];
            short hh = f2bf(cvt.f);
            h[ii][kk] = hh;
            l[ii][kk] = f2bf(cvt.f - bf2f(hh));
          }
        } else {
#pragma unroll
          for (int kk = 0; kk < 4; ++kk) {
            h[ii][kk] = (short)(uu[kk] >> 16);
            l[ii][kk] = (short)(uu[kk] & 0xffffu);
          }
        }
      }
#pragma unroll
      for (int kk = 0; kk < 4; ++kk) {
        short4v vh = {h[0][kk], h[1][kk], h[2][kk], h[3][kk]};
        short4v vl = {l[0][kk], l[1][kk], l[2][kk], l[3][kk]};
        *(short4v*)&rT[kq * 4 + kk][iq * 4] = vh;
        *(short4v*)&rT[kq * 4 + kk][32 + iq * 4] = vl;
      }
    }
    {
      short h[4][4], l[4][4];
#pragma unroll
      for (int ii = 0; ii < 4; ++ii) {
        int gi = ib + iq * 4 + ii;
        float4 xx = make_float4(0.f, 0.f, 0.f, 0.f);
        float sc = 0.0f;
        if (gi < iend) {
          xx = *(const float4*)(data + (size_t)gi * DIMD + d0 + kq * 4);
          sc = inv_norm[gi];
        }
        float vv[4] = {xx.x * sc, xx.y * sc, xx.z * sc, xx.w * sc};
#pragma unroll
        for (int kk = 0; kk < 4; ++kk) {
          short hh = f2bf(vv[kk]);
          h[ii][kk] = hh;
          l[ii][kk] = f2bf(vv[kk] - bf2f(hh));
        }
      }
#pragma unroll
      for (int kk = 0; kk < 4; ++kk) {
        short4v vh = {h[0][kk], h[1][kk], h[2][kk], h[3][kk]};
        short4v vl = {l[0][kk], l[1][kk], l[2][kk], l[3][kk]};
        *(short4v*)&xT[kq * 4 + kk][iq * 4] = vh;
        *(short4v*)&xT[kq * 4 + kk][32 + iq * 4] = vl;
      }
    }
    __syncthreads();
    short8 ah[4], al[4], bh[4], bl[4];
#pragma unroll
    for (int mt = 0; mt < 4; ++mt) {
      int kr = wk * 64 + mt * 16 + lx;
      ah[mt] = *(const short8*)&rT[kr][q * 8];
      al[mt] = *(const short8*)&rT[kr][32 + q * 8];
    }
#pragma unroll
    for (int nt = 0; nt < 4; ++nt) {
      int dr = wd * 64 + nt * 16 + lx;
      bh[nt] = *(const short8*)&xT[dr][q * 8];
      bl[nt] = *(const short8*)&xT[dr][32 + q * 8];
    }
#pragma unroll
    for (int mt = 0; mt < 4; ++mt)
#pragma unroll
      for (int nt = 0; nt < 4; ++nt) {
        acc[mt][nt] = __builtin_amdgcn_mfma_f32_16x16x32_bf16(
            ah[mt], bh[nt], acc[mt][nt], 0, 0, 0);
        acc[mt][nt] = __builtin_amdgcn_mfma_f32_16x16x32_bf16(
            ah[mt], bl[nt], acc[mt][nt], 0, 0, 0);
        acc[mt][nt] = __builtin_amdgcn_mfma_f32_16x16x32_bf16(
            al[mt], bh[nt], acc[mt][nt], 0, 0, 0);
      }
    __syncthreads();
  }
#pragma unroll
  for (int mt = 0; mt < 4; ++mt)
#pragma unroll
    for (int nt = 0; nt < 4; ++nt)
#pragma unroll
      for (int reg = 0; reg < 4; ++reg) {
        int k = k0 + wk * 64 + mt * 16 + q * 4 + reg;
        int d = d0 + wd * 64 + nt * 16 + lx;
        atomicAdd(&mu_acc[(size_t)k * DIMD + d], acc[mt][nt][reg]);
      }
}

extern "C" void kernel_launch(void* const* d_in, const int* in_sizes, int n_in,
                              void* d_out, int out_size, void* d_ws,
                              size_t ws_size, hipStream_t stream) {
  const float* embeds = (const float*)d_in[0];
  const float* temp_p = (const float*)d_in[1];
  const float* init = (const float*)d_in[2];
  int n = in_sizes[0] / DIMD;  // 100000

  float* out_mu = (float*)d_out;                       // [256*512]
  float* out_r = (float*)d_out + (size_t)KCL * DIMD;   // [n*256]

  char* base = (char*)d_ws;
  size_t off = 0;
  auto alloc = [&](size_t bytes) {
    char* p = base + off;
    off += (bytes + 255) & ~(size_t)255;
    return p;
  };
  float* inv_norm = (float*)alloc((size_t)n * 4);
  float* mu_acc = (float*)alloc((size_t)KCL * DIMD * 4);
  float* colsum = (float*)alloc(1024);
  short* mu_hi = (short*)alloc((size_t)KCL * DIMD * 2);
  short* mu_lo = (short*)alloc((size_t)KCL * DIMD * 2);

  const size_t PL = (size_t)n * DIMD * 2;   // one bf16 plane
  const size_t RTB = (size_t)n * KCL * 4;   // packed rT scratch
  const size_t SLACK = 4096;

  short *xT_hi = nullptr, *xT_lo = nullptr, *pl_hi = nullptr, *pl_lo = nullptr;
  unsigned* rT2 = nullptr;
  int tier = 0;
  if (off + 2 * PL + SLACK <= ws_size) {
    xT_hi = (short*)alloc(PL);
    xT_lo = (short*)alloc(PL);
    tier = 1;
  }
  if (tier == 1 && off + 2 * PL + SLACK <= ws_size) {
    pl_hi = (short*)alloc(PL);
    pl_lo = (short*)alloc(PL);
    tier = 2;
  }
  if (tier == 2 && off + RTB + SLACK <= ws_size) {
    rT2 = (unsigned*)alloc(RTB);
    tier = 3;
  }

  row_norms_conv_k<<<(n + 3) / 4, 256, 0, stream>>>(embeds, inv_norm, pl_hi,
                                                    pl_lo, n, tier >= 2);
  if (tier >= 1)
    transpose_k<<<dim3((n + 63) / 64, DIMD / 64), 256, 0, stream>>>(
        embeds, inv_norm, xT_hi, xT_lo, n);
  mu_norm_k<<<KCL, 256, 0, stream>>>(init, colsum, mu_hi, mu_lo, mu_acc,
                                     colsum, 0);

  int chunk_v3 = (((n + NCH3 - 1) / NCH3) + 31) & ~31;
  int dist_grid = (n + 63) / 64;

  for (int it = 0; it <= 10; ++it) {
    int wf32 = (it == 10) ? 1 : 0;
    unsigned* rta = (wf32 && tier >= 3) ? rT2 : nullptr;
    if (tier >= 2)
      dist_k<1, 1><<<dist_grid, 256, 0, stream>>>(
          embeds, inv_norm, pl_hi, pl_lo, mu_hi, mu_lo, (unsigned*)out_r,
          out_r, rta, wf32, colsum, temp_p, n);
    else if (tier == 1)
      dist_k<0, 1><<<dist_grid, 256, 0, stream>>>(
          embeds, inv_norm, pl_hi, pl_lo, mu_hi, mu_lo, (unsigned*)out_r,
          out_r, nullptr, wf32, colsum, temp_p, n);
    else
      dist_k<0, 0><<<dist_grid, 256, 0, stream>>>(
          embeds, inv_norm, pl_hi, pl_lo, mu_hi, mu_lo, (unsigned*)out_r,
          out_r, nullptr, wf32, colsum, temp_p, n);

    if (it < 10) {
      if (tier >= 1)
        update_v3_k<<<8 * NCH3, 256, 0, stream>>>(
            (const unsigned*)out_r, xT_hi, xT_lo, mu_acc, n, chunk_v3);
      else
        update_mfma_k<<<dim3(8, NSPLIT), 256, 0, stream>>>(
            (const unsigned*)out_r, 0, embeds, inv_norm, mu_acc, n);
      mu_norm_k<<<KCL, 256, 0, stream>>>(mu_acc, colsum, mu_hi, mu_lo, mu_acc,
                                         colsum, 1);
    } else {
      if (tier >= 3)
        update_v3_k<<<8 * NCH3, 256, 0, stream>>>(rT2, xT_hi, xT_lo, mu_acc,
                                                  n, chunk_v3);
      else
        update_mfma_k<<<dim3(8, NSPLIT), 256, 0, stream>>>(
            (const unsigned*)out_r, 1, embeds, inv_norm, mu_acc, n);
      final_mu_k<<<KCL, 256, 0, stream>>>(mu_acc, colsum, out_mu);
    }
  }
}